// Round 12
// baseline (1071.121 us; speedup 1.0000x reference)
//
#include <hip/hip_runtime.h>
#include <math.h>

#define NB 64
#define NN 1024
#define NC 128
#define NK 512

// DIAGNOSTIC ROUND: each kernel body wrapped in an idempotent rep-loop to
// amplify per-dispatch duration past the ~155us harness fills, so all three
// kernels appear in rocprof top-5 with per-kernel counters. Results are
// identical to single-rep (same values rewritten). Revert reps next round.
#define REP1 32
#define REP2 24
#define REP3 16

// K1: fused score+rank+xpool (R11 structure).
__global__ __launch_bounds__(1024) void scorerank_kernel(
    const float* __restrict__ x, const float* __restrict__ w,
    int* __restrict__ perm, float* __restrict__ gate, int* __restrict__ inv,
    float* __restrict__ x_pool)
{
    __shared__ __align__(16) double s[NN];   // 8 KB
    __shared__ int rp[1024];                 // 4 KB
    __shared__ double s_rnw;
    __shared__ int sel_nr[256];
    __shared__ float sel_g[256];
    __shared__ int scount;
    const int i = blockIdx.x;
    const int b = (i & 7) + ((i >> 5) << 3); // graph (same-XCD groups of 4)
    const int q = (i >> 3) & 3;              // quarter
    const int t = threadIdx.x;

    for (int rep = 0; rep < REP1; ++rep) {
        // ---- score: 16 lanes/row, 64 rows/pass, 16 passes ----
        const int c0 = (t & 15) * 8;
        const float4 wa = *(const float4*)(w + c0);
        const float4 wb = *(const float4*)(w + c0 + 4);
        #pragma unroll 4
        for (int pass = 0; pass < 16; ++pass) {
            int row = pass * 64 + (t >> 4);
            const float* xr = x + ((size_t)b * NN + row) * NC + c0;
            float4 a  = *(const float4*)xr;
            float4 bb = *(const float4*)(xr + 4);
            double acc = (double)a.x * wa.x + (double)a.y * wa.y
                       + (double)a.z * wa.z + (double)a.w * wa.w
                       + (double)bb.x * wb.x + (double)bb.y * wb.y
                       + (double)bb.z * wb.z + (double)bb.w * wb.w;
            acc += __shfl_xor(acc, 1, 64);
            acc += __shfl_xor(acc, 2, 64);
            acc += __shfl_xor(acc, 4, 64);
            acc += __shfl_xor(acc, 8, 64);
            if ((t & 15) == 0) s[row] = acc;
        }
        if (t < 64) {
            double p = (double)w[t] * (double)w[t]
                     + (double)w[t + 64] * (double)w[t + 64];
            #pragma unroll
            for (int off = 32; off > 0; off >>= 1)
                p += __shfl_xor(p, off, 64);
            if (t == 0) s_rnw = 1.0 / sqrt(p);
        }
        if (t == 0) scount = 0;
        __syncthreads();

        // ---- rank ----
        const int n  = q * 256 + (t & 255);
        const int jc = t >> 8;
        const double my = s[n];
        int r = 0;
        #pragma unroll 8
        for (int j = jc * 256; j < jc * 256 + 256; j += 2) {
            double2 o = *(const double2*)&s[j];
            r += (o.x > my) || ((o.x == my) && (j < n));
            r += (o.y > my) || ((o.y == my) && (j + 1 < n));
        }
        rp[t] = r;
        __syncthreads();
        if (jc == 0) {
            int rr = rp[t] + rp[t + 256] + rp[t + 512] + rp[t + 768];
            inv[b * NN + n] = (rr < NK) ? rr : -1;
            if (rr < NK) {
                float gv = (float)tanh(my * s_rnw);
                perm[b * NK + rr] = n;
                gate[b * NK + rr] = gv;
                int slot = atomicAdd(&scount, 1);
                sel_nr[slot] = (n << 16) | rr;
                sel_g[slot]  = gv;
            }
        }
        __syncthreads();

        // ---- xpool for this block's selections ----
        const int cnt = scount;
        const int rowSlot = t >> 5;
        const int lane = t & 31;
        for (int base = 0; base < cnt; base += 32) {
            int idx = base + rowSlot;
            if (idx < cnt) {
                int nr = sel_nr[idx];
                int n2 = nr >> 16, rr = nr & 0xffff;
                float g = sel_g[idx];
                float4 v = *(const float4*)(x + ((size_t)b * NN + n2) * NC + lane * 4);
                v.x *= g; v.y *= g; v.z *= g; v.w *= g;
                *(float4*)(x_pool + ((size_t)b * NK + rr) * NC + lane * 4) = v;
            }
        }
        __syncthreads();
    }
}

// K2: pure scan (R11 structure).
__global__ __launch_bounds__(1024) void adj_scan_kernel(
    const float* __restrict__ adj, const int* __restrict__ perm,
    const int* __restrict__ inv, unsigned* __restrict__ bm)
{
    __shared__ unsigned bits[64 * 17];    // 4.25 KB
    __shared__ int sinv[NN];              // 4 KB
    const int b = blockIdx.x >> 3;
    const int chunk = blockIdx.x & 7;
    const int t = threadIdx.x;

    for (int rep = 0; rep < REP2; ++rep) {
        for (int idx = t; idx < 64 * 17; idx += 1024) bits[idx] = 0;
        for (int idx = t; idx < NN; idx += 1024) sinv[idx] = inv[b * NN + idx];
        __syncthreads();

        const float* ab = adj + (size_t)b * NN * NN;
        const int* permb = perm + b * NK + chunk * 64;
        const int g  = t >> 8;
        const int lt = t & 255;

        int il = g;
        float4 v0 = *(const float4*)(ab + (size_t)permb[il] * NN + lt * 4);
        float4 v1 = *(const float4*)(ab + (size_t)permb[il + 4] * NN + lt * 4);
        float4 v2 = *(const float4*)(ab + (size_t)permb[il + 8] * NN + lt * 4);
        float4 v3 = *(const float4*)(ab + (size_t)permb[il + 12] * NN + lt * 4);
        for (int it = 0; it < 16; ++it) {
            float4 vn = v0;
            if (it < 12)
                vn = *(const float4*)(ab + (size_t)permb[il + 16] * NN + lt * 4);
            #pragma unroll
            for (int u = 0; u < 4; ++u) {
                if (((const float*)&v0)[u] != 0.0f) {
                    int j = sinv[lt * 4 + u];
                    if (j >= 0)
                        atomicOr(&bits[il * 17 + (j >> 5)], 1u << (j & 31));
                }
            }
            v0 = v1; v1 = v2; v2 = v3; v3 = vn; il += 4;
        }
        __syncthreads();
        {
            int dil = t & 63, w = t >> 6;
            bm[(size_t)b * 8192 + w * 512 + chunk * 64 + dil] = bits[dil * 17 + w];
        }
        __syncthreads();
    }
}

// K3: bitmap -> adj_pooled (R11 structure).
__global__ __launch_bounds__(1024) void adj_write_kernel(
    const unsigned* __restrict__ bm, float* __restrict__ out)
{
    __shared__ unsigned tcb[2 * 512];
    __shared__ unsigned fws[64 * 17];
    const int b = blockIdx.x >> 3;
    const int slab = blockIdx.x & 7;
    const int t = threadIdx.x;
    const unsigned* bmb = bm + (size_t)b * 8192;

    for (int rep = 0; rep < REP3; ++rep) {
        {
            int e = t >> 9, j = t & 511;
            tcb[t] = bmb[(slab * 2 + e) * 512 + j];
        }
        {
            int il = t & 63, wi = t >> 6;
            fws[il * 17 + wi] = bmb[wi * 512 + slab * 64 + il];
        }
        __syncthreads();

        float* ob = out + ((size_t)b * NK + slab * 64) * NK;
        #pragma unroll
        for (int it = 0; it < 8; ++it) {
            int lid = it * 1024 + t;
            int i_loc = lid >> 7;
            int i = slab * 64 + i_loc;
            int j4 = (lid & 127) * 4;
            unsigned fw = fws[i_loc * 17 + (j4 >> 5)];
            uint4 tq = *(const uint4*)&tcb[(i_loc >> 5) * 512 + j4];
            float4 res;
            float* rpn = (float*)&res;
            const unsigned* tp = (const unsigned*)&tq;
            #pragma unroll
            for (int e = 0; e < 4; ++e) {
                unsigned bit = ((fw >> ((j4 + e) & 31)) | (tp[e] >> (i & 31))) & 1u;
                float f = (float)bit;
                if (i == j4 + e) f += 1.0f;
                rpn[e] = f;
            }
            *(float4*)(ob + (size_t)i_loc * NK + j4) = res;
        }
        __syncthreads();
    }
}

extern "C" void kernel_launch(void* const* d_in, const int* in_sizes, int n_in,
                              void* d_out, int out_size, void* d_ws, size_t ws_size,
                              hipStream_t stream) {
    const float* x   = (const float*)d_in[0];
    const float* adj = (const float*)d_in[1];
    const float* w   = (const float*)d_in[2];
    float* out = (float*)d_out;

    char* p = (char*)d_ws;
    unsigned* bm   = (unsigned*)p;  p += sizeof(unsigned) * NB * 16 * NK; // 2 MB
    int*      perm = (int*)p;       p += sizeof(int) * NB * NK;           // 128 KB
    float*    gate = (float*)p;     p += sizeof(float) * NB * NK;         // 128 KB
    int*      inv  = (int*)p;                                             // 256 KB

    float* x_pool     = out;                           // NB*NK*NC
    float* adj_pooled = out + (size_t)NB * NK * NC;    // NB*NK*NK

    scorerank_kernel<<<NB * 4, 1024, 0, stream>>>(x, w, perm, gate, inv, x_pool);
    adj_scan_kernel<<<NB * 8, 1024, 0, stream>>>(adj, perm, inv, bm);
    adj_write_kernel<<<NB * 8, 1024, 0, stream>>>(bm, adj_pooled);
}

// Round 13
// 56.181 us; speedup vs baseline: 19.0657x; 19.0657x over previous
//
#include <hip/hip_runtime.h>
#include <math.h>

#define NB 64
#define NN 1024
#define NC 128
#define NK 512

// K1a: partitioned fp64 score — 4 blocks/graph, each scores a DISJOINT
// quarter (no redundancy). 16 lanes/row, 64 rows/pass, 4 passes.
__global__ __launch_bounds__(1024) void score_kernel(
    const float* __restrict__ x, const float* __restrict__ w,
    double* __restrict__ sacc)
{
    const int i = blockIdx.x;            // 256 blocks
    const int b = i >> 2, q = i & 3;
    const int t = threadIdx.x;
    const int c0 = (t & 15) * 8;
    const float4 wa = *(const float4*)(w + c0);
    const float4 wb = *(const float4*)(w + c0 + 4);
    #pragma unroll
    for (int pass = 0; pass < 4; ++pass) {
        int row = q * 256 + pass * 64 + (t >> 4);
        const float* xr = x + ((size_t)b * NN + row) * NC + c0;
        float4 a  = *(const float4*)xr;
        float4 bb = *(const float4*)(xr + 4);
        double acc = (double)a.x * wa.x + (double)a.y * wa.y
                   + (double)a.z * wa.z + (double)a.w * wa.w
                   + (double)bb.x * wb.x + (double)bb.y * wb.y
                   + (double)bb.z * wb.z + (double)bb.w * wb.w;
        acc += __shfl_xor(acc, 1, 64);
        acc += __shfl_xor(acc, 2, 64);
        acc += __shfl_xor(acc, 4, 64);
        acc += __shfl_xor(acc, 8, 64);
        if ((t & 15) == 0) sacc[(size_t)b * NN + row] = acc;
    }
}

// K1b: rank via packed u64 keys + xpool. 8 blocks/graph (XCD-grouped),
// 1024 threads, 2 blocks/CU. key = (mono(score) & ~1023) | (1023-idx):
// single unsigned compare == (score desc, idx asc) total order; dropping
// 10 low mantissa bits is ~7 orders of magnitude below min score gaps.
__global__ __launch_bounds__(1024) void rank_xpool_kernel(
    const double* __restrict__ sacc, const float* __restrict__ x,
    const float* __restrict__ w, int* __restrict__ perm,
    float* __restrict__ gate, int* __restrict__ inv,
    float* __restrict__ x_pool)
{
    __shared__ __align__(16) unsigned long long keys[NN];  // 8 KB
    __shared__ int rp[1024];                               // 4 KB
    __shared__ double s_rnw;
    __shared__ int sel_nr[128];
    __shared__ float sel_g[128];
    __shared__ int scount;
    const int i = blockIdx.x;                // 512 blocks
    const int b = (i & 7) + ((i >> 6) << 3); // graph (same-XCD groups of 8)
    const int h = (i >> 3) & 7;              // node octant
    const int t = threadIdx.x;

    {   // pack key for node t
        double sv = sacc[(size_t)b * NN + t];
        long long bits = __double_as_longlong(sv);
        unsigned long long mono =
            (unsigned long long)(bits ^ ((bits >> 63) | 0x8000000000000000LL));
        keys[t] = (mono & ~1023ULL) | (unsigned long long)(1023 - t);
    }
    if (t < 64) {    // 1/||w|| in double via wave shuffle
        double p = (double)w[t] * (double)w[t]
                 + (double)w[t + 64] * (double)w[t + 64];
        #pragma unroll
        for (int off = 32; off > 0; off >>= 1)
            p += __shfl_xor(p, off, 64);
        if (t == 0) s_rnw = 1.0 / sqrt(p);
    }
    if (t == 0) scount = 0;
    __syncthreads();

    // rank: node n = h*128+(t&127); j-chunk jc = t>>7 (8-way split).
    const int n  = h * 128 + (t & 127);
    const int jc = t >> 7;
    const unsigned long long mykey = keys[n];
    int r = 0;
    #pragma unroll 8
    for (int j2 = 0; j2 < 64; ++j2) {
        ulonglong2 kk = *(const ulonglong2*)&keys[jc * 128 + j2 * 2];
        r += (kk.x > mykey);
        r += (kk.y > mykey);
    }
    rp[t] = r;
    __syncthreads();
    if (t < 128) {
        int rr = 0;
        #pragma unroll
        for (int c = 0; c < 8; ++c) rr += rp[c * 128 + t];
        int n2 = h * 128 + t;
        inv[b * NN + n2] = (rr < NK) ? rr : -1;
        if (rr < NK) {
            double sv = sacc[(size_t)b * NN + n2];
            float gv = (float)tanh(sv * s_rnw);
            perm[b * NK + rr] = n2;
            gate[b * NK + rr] = gv;
            int slot = atomicAdd(&scount, 1);
            sel_nr[slot] = (n2 << 16) | rr;
            sel_g[slot]  = gv;
        }
    }
    __syncthreads();

    // xpool for this block's selected nodes (<=128): 32 lanes/row.
    const int cnt = scount;
    const int rowSlot = t >> 5;
    const int lane = t & 31;
    for (int base = 0; base < cnt; base += 32) {
        int idx = base + rowSlot;
        if (idx < cnt) {
            int nr = sel_nr[idx];
            int n2 = nr >> 16, rr = nr & 0xffff;
            float g = sel_g[idx];
            float4 v = *(const float4*)(x + ((size_t)b * NN + n2) * NC + lane * 4);
            v.x *= g; v.y *= g; v.z *= g; v.w *= g;
            *(float4*)(x_pool + ((size_t)b * NK + rr) * NC + lane * 4) = v;
        }
    }
}

// K2: pure scan — 8 blocks/graph, 64 pooled rows each, 4-deep row prefetch;
// forward bits only into LDS [64][17]; dump COL-MAJOR to bm[b][w][j].
__global__ __launch_bounds__(1024) void adj_scan_kernel(
    const float* __restrict__ adj, const int* __restrict__ perm,
    const int* __restrict__ inv, unsigned* __restrict__ bm)
{
    __shared__ unsigned bits[64 * 17];    // 4.25 KB
    __shared__ int sinv[NN];              // 4 KB
    const int b = blockIdx.x >> 3;
    const int chunk = blockIdx.x & 7;     // 64 pooled rows each
    const int t = threadIdx.x;
    for (int idx = t; idx < 64 * 17; idx += 1024) bits[idx] = 0;
    for (int idx = t; idx < NN; idx += 1024) sinv[idx] = inv[b * NN + idx];
    __syncthreads();

    const float* ab = adj + (size_t)b * NN * NN;
    const int* permb = perm + b * NK + chunk * 64;
    const int g  = t >> 8;               // local row-group 0..3
    const int lt = t & 255;

    int il = g;                          // rows g, g+4, ..., g+60 (16 iters)
    float4 v0 = *(const float4*)(ab + (size_t)permb[il] * NN + lt * 4);
    float4 v1 = *(const float4*)(ab + (size_t)permb[il + 4] * NN + lt * 4);
    float4 v2 = *(const float4*)(ab + (size_t)permb[il + 8] * NN + lt * 4);
    float4 v3 = *(const float4*)(ab + (size_t)permb[il + 12] * NN + lt * 4);
    for (int it = 0; it < 16; ++it) {
        float4 vn = v0;
        if (it < 12)                     // 4-deep prefetch
            vn = *(const float4*)(ab + (size_t)permb[il + 16] * NN + lt * 4);
        #pragma unroll
        for (int u = 0; u < 4; ++u) {
            if (((const float*)&v0)[u] != 0.0f) {
                int j = sinv[lt * 4 + u];
                if (j >= 0)
                    atomicOr(&bits[il * 17 + (j >> 5)], 1u << (j & 31));
            }
        }
        v0 = v1; v1 = v2; v2 = v3; v3 = vn; il += 4;
    }
    __syncthreads();
    {
        int dil = t & 63, w = t >> 6;
        bm[(size_t)b * 8192 + w * 512 + chunk * 64 + dil] = bits[dil * 17 + w];
    }
}

// K3: adj_pooled[b,i,j] = (fw(i,j) | trans(j,i)) + (i==j).
// 8 blocks/graph x 64 output rows, 1024 threads; slab-only LDS staging.
__global__ __launch_bounds__(1024) void adj_write_kernel(
    const unsigned* __restrict__ bm, float* __restrict__ out)
{
    __shared__ unsigned tcb[2 * 512];
    __shared__ unsigned fws[64 * 17];
    const int b = blockIdx.x >> 3;
    const int slab = blockIdx.x & 7;
    const int t = threadIdx.x;
    const unsigned* bmb = bm + (size_t)b * 8192;
    {
        int e = t >> 9, j = t & 511;
        tcb[t] = bmb[(slab * 2 + e) * 512 + j];
    }
    {
        int il = t & 63, wi = t >> 6;
        fws[il * 17 + wi] = bmb[wi * 512 + slab * 64 + il];
    }
    __syncthreads();

    float* ob = out + ((size_t)b * NK + slab * 64) * NK;
    #pragma unroll
    for (int it = 0; it < 8; ++it) {
        int lid = it * 1024 + t;
        int i_loc = lid >> 7;
        int i = slab * 64 + i_loc;
        int j4 = (lid & 127) * 4;
        unsigned fw = fws[i_loc * 17 + (j4 >> 5)];
        uint4 tq = *(const uint4*)&tcb[(i_loc >> 5) * 512 + j4];
        float4 res;
        float* rpn = (float*)&res;
        const unsigned* tp = (const unsigned*)&tq;
        #pragma unroll
        for (int e = 0; e < 4; ++e) {
            unsigned bit = ((fw >> ((j4 + e) & 31)) | (tp[e] >> (i & 31))) & 1u;
            float f = (float)bit;
            if (i == j4 + e) f += 1.0f;
            rpn[e] = f;
        }
        *(float4*)(ob + (size_t)i_loc * NK + j4) = res;
    }
}

extern "C" void kernel_launch(void* const* d_in, const int* in_sizes, int n_in,
                              void* d_out, int out_size, void* d_ws, size_t ws_size,
                              hipStream_t stream) {
    const float* x   = (const float*)d_in[0];
    const float* adj = (const float*)d_in[1];
    const float* w   = (const float*)d_in[2];
    float* out = (float*)d_out;

    char* p = (char*)d_ws;
    double*   sacc = (double*)p;    p += sizeof(double) * NB * NN;        // 512 KB
    unsigned* bm   = (unsigned*)p;  p += sizeof(unsigned) * NB * 16 * NK; // 2 MB
    int*      perm = (int*)p;       p += sizeof(int) * NB * NK;           // 128 KB
    float*    gate = (float*)p;     p += sizeof(float) * NB * NK;         // 128 KB
    int*      inv  = (int*)p;                                             // 256 KB

    float* x_pool     = out;                           // NB*NK*NC
    float* adj_pooled = out + (size_t)NB * NK * NC;    // NB*NK*NK

    score_kernel<<<NB * 4, 1024, 0, stream>>>(x, w, sacc);
    rank_xpool_kernel<<<NB * 8, 1024, 0, stream>>>(sacc, x, w, perm, gate, inv, x_pool);
    adj_scan_kernel<<<NB * 8, 1024, 0, stream>>>(adj, perm, inv, bm);
    adj_write_kernel<<<NB * 8, 1024, 0, stream>>>(bm, adj_pooled);
}